// Round 14
// baseline (181.894 us; speedup 1.0000x reference)
//
#include <hip/hip_runtime.h>

// ============================================================================
// ATTRIBUTION ROUND (take 2): kernels VERBATIM from the round-8 119.8us bench;
// only the launcher differs: k_bucket_agg launched 3x (idempotent).
// dur - 119.8 = 2*t(k2). (r13's attempt corrupted phase C with shfl folds
// that summed across different quads' nodes -- removed; r8 phase C has each
// quad-lane privately accumulate its 4 cols + a complete private den.)
// ============================================================================

#define NODE_DIM 128
#define OUT_DIM  64
#define NEG_SLOPE 0.01f
#define EPB   4096     // edges per partition block (256 thr x 16)
#define CAPC  64       // capacity per (bucket, partition-block) chunk (mean ~21, 9.4-sigma)
#define MAXB  4800     // max edges per bucket staged in LDS (mean 4096, +11 sigma)

typedef __attribute__((ext_vector_type(8))) short short8;
typedef __attribute__((ext_vector_type(4))) short short4v;
typedef __attribute__((ext_vector_type(4))) float float4e;

__device__ __forceinline__ unsigned short f2bf(float f) {
    unsigned u = __float_as_uint(f);
    unsigned r = (u + 0x7FFFu + ((u >> 16) & 1u)) >> 16;
    return (unsigned short)r;
}
__device__ __forceinline__ float bf2f(unsigned short v) {
    return __uint_as_float((unsigned)v << 16);
}
__device__ __forceinline__ void split_bf(float v, short& hi, short& lo) {
    unsigned short h = f2bf(v);
    float r = v - bf2f(h);
    hi = (short)h;
    lo = (short)f2bf(r);
}

// ---- K1: blocks [0,PB): MFMA projection; blocks [PB,PB+nblkP): partition ---
__global__ __launch_bounds__(256) void k_proj_part(
    const float* __restrict__ h, const float* __restrict__ Wf,
    const float* __restrict__ Wa,
    unsigned short* __restrict__ zbf,
    float* __restrict__ s_src, float* __restrict__ s_dst,
    const int* __restrict__ src, const int* __restrict__ dst,
    int* __restrict__ chunks, int* __restrict__ bhist,
    int N, int E, int PB, int nblkP)
{
    __shared__ union {
        short w[16384];                 // [0..8191]=hi, [8192..16383]=lo (frag order)
        unsigned short zt[4][16][68];   // per-wave transpose tile (aliased AFTER barrier)
    } uni;
    __shared__ int cnt[256];

    if (blockIdx.x >= (unsigned)PB) {
        const int blk = blockIdx.x - PB;
        const int t = threadIdx.x;
        cnt[t] = 0;
        __syncthreads();
        const int e0 = blk * EPB + t * 16;
        if (e0 < E) {
            int ne = E - e0; if (ne > 16) ne = 16;
            if (ne == 16) {
                int db[16], sb[16];
                const int4* dp = (const int4*)(dst + e0);
                const int4* sp = (const int4*)(src + e0);
                #pragma unroll
                for (int q = 0; q < 4; ++q) {
                    int4 dv = dp[q], svv = sp[q];
                    db[q*4+0]=dv.x; db[q*4+1]=dv.y; db[q*4+2]=dv.z; db[q*4+3]=dv.w;
                    sb[q*4+0]=svv.x; sb[q*4+1]=svv.y; sb[q*4+2]=svv.z; sb[q*4+3]=svv.w;
                }
                #pragma unroll
                for (int k = 0; k < 16; ++k) {
                    int d = db[k];
                    int bk = d >> 8;
                    int r = atomicAdd(&cnt[bk], 1);
                    if (r < CAPC)
                        chunks[((size_t)bk * nblkP + blk) * CAPC + r] = ((d & 255) << 17) | sb[k];
                }
            } else {
                for (int k = 0; k < ne; ++k) {
                    int d = dst[e0 + k];
                    int bk = d >> 8;
                    int r = atomicAdd(&cnt[bk], 1);
                    if (r < CAPC)
                        chunks[((size_t)bk * nblkP + blk) * CAPC + r] = ((d & 255) << 17) | src[e0 + k];
                }
            }
        }
        __syncthreads();
        bhist[t * nblkP + blk] = (cnt[t] < CAPC) ? cnt[t] : CAPC;
        return;
    }

    const int t    = threadIdx.x;
    const int wv   = t >> 6;
    const int lane = t & 63;
    const int m    = lane & 15;
    const int quad = lane >> 4;
    const int row0 = blockIdx.x * 64 + wv * 16;

    // --- cooperative W stage -> LDS (frag order) ----------------------------
    {
        short* wh = uni.w;
        short* wl = uni.w + 8192;
        for (int s = t; s < 1024; s += 256) {
            int combo = s >> 6;
            int ln    = s & 63;
            int c = combo >> 2, t4 = combo & 3;
            int col = c * 16 + (ln & 15);
            int kq  = t4 * 32 + (ln >> 4) * 8;
            #pragma unroll
            for (int j = 0; j < 8; ++j) {
                short hi, lo;
                split_bf(Wf[(kq + j) * OUT_DIM + col], hi, lo);
                wh[s * 8 + j] = hi;
                wl[s * 8 + j] = lo;
            }
        }
    }
    __syncthreads();

    int rowc = row0 + m; if (rowc > N - 1) rowc = N - 1;
    const float* hrow = h + (size_t)rowc * NODE_DIM;
    short8 Ahi[4], Alo[4];
    #pragma unroll
    for (int t4 = 0; t4 < 4; ++t4) {
        float4e v0 = *(const float4e*)(hrow + t4 * 32 + quad * 8);
        float4e v1 = *(const float4e*)(hrow + t4 * 32 + quad * 8 + 4);
        #pragma unroll
        for (int j = 0; j < 4; ++j) {
            short hi, lo;
            split_bf(v0[j], hi, lo);
            Ahi[t4][j] = hi; Alo[t4][j] = lo;
            split_bf(v1[j], hi, lo);
            Ahi[t4][4 + j] = hi; Alo[t4][4 + j] = lo;
        }
    }

    float ps[4] = {0.f, 0.f, 0.f, 0.f};
    float pd[4] = {0.f, 0.f, 0.f, 0.f};
    unsigned short z16[16];

    const short* wh = uni.w;
    const short* wl = uni.w + 8192;
    #pragma unroll
    for (int c = 0; c < 4; ++c) {
        float4e acc = {0.f, 0.f, 0.f, 0.f};
        #pragma unroll
        for (int t4 = 0; t4 < 4; ++t4) {
            int slot = (c * 4 + t4) * 64 + lane;
            short8 bh = *(const short8*)(wh + slot * 8);   // ds_read_b128, conflict-free
            short8 bl = *(const short8*)(wl + slot * 8);
            acc = __builtin_amdgcn_mfma_f32_16x16x32_bf16(Alo[t4], bh, acc, 0, 0, 0);
            acc = __builtin_amdgcn_mfma_f32_16x16x32_bf16(Ahi[t4], bl, acc, 0, 0, 0);
            acc = __builtin_amdgcn_mfma_f32_16x16x32_bf16(Ahi[t4], bh, acc, 0, 0, 0);
        }
        int col = c * 16 + m;
        float was = Wa[col];
        float wad = Wa[OUT_DIM + col];
        #pragma unroll
        for (int r = 0; r < 4; ++r) {
            z16[c * 4 + r] = f2bf(acc[r]);
            ps[r] = fmaf(acc[r], was, ps[r]);
            pd[r] = fmaf(acc[r], wad, pd[r]);
        }
    }

    #pragma unroll
    for (int r = 0; r < 4; ++r) {
        #pragma unroll
        for (int off = 1; off < 16; off <<= 1) {
            ps[r] += __shfl_xor(ps[r], off, 64);
            pd[r] += __shfl_xor(pd[r], off, 64);
        }
    }
    if (m == 0) {
        #pragma unroll
        for (int r = 0; r < 4; ++r) {
            int nrow = row0 + quad * 4 + r;
            if (nrow < N) { s_src[nrow] = ps[r]; s_dst[nrow] = pd[r]; }
        }
    }

    // --- zbf epilogue: transpose via LDS, 2 coalesced short8 stores/wave ----
    __syncthreads();     // all waves done reading W before aliasing uni
    {
        unsigned short (*zt)[68] = uni.zt[wv];
        #pragma unroll
        for (int c = 0; c < 4; ++c)
            #pragma unroll
            for (int r = 0; r < 4; ++r)
                zt[quad * 4 + r][c * 16 + m] = z16[c * 4 + r];
        short* zb = (short*)zbf;
        #pragma unroll
        for (int i = 0; i < 2; ++i) {
            int r    = i * 8 + (lane >> 3);
            int colb = (lane & 7) * 8;
            short8 zz = *(const short8*)&zt[r][colb];
            int grow = row0 + r;
            if (grow < N)
                *(short8*)(zb + (size_t)grow * OUT_DIM + colb) = zz;
        }
    }
}

// ---- K2: one block per 256-node bucket, 1024 threads (r8 verbatim) ---------
// Phase C: quad-per-node -- EACH LANE of a quad privately accumulates its 4
// output cols AND a complete private den (all 16 lanes iterate the same edge
// list). NO cross-lane reduction.
__global__ __launch_bounds__(1024) void k_bucket_agg(
    const int* __restrict__ chunks, const int* __restrict__ bhist,
    const float* __restrict__ s_src, const float* __restrict__ s_dst,
    const unsigned short* __restrict__ zbf,
    float* __restrict__ out, int N, int nblkP)
{
    __shared__ int   sSrc[MAXB];
    __shared__ float xs[MAXB];
    __shared__ int cntN[256], rsN[256], curN[256], sscan[256];
    const int b = blockIdx.x;
    const int t = threadIdx.x;
    const int wid = t >> 6, lane = t & 63;
    const int nodeBase = b * 256;

    if (t < 256) cntN[t] = 0;
    __syncthreads();

    // walk 1: count per node
    for (int c = wid; c < nblkP; c += 16) {
        int cc = bhist[b * nblkP + c];
        if (lane < cc) {
            int val = chunks[((size_t)b * nblkP + c) * CAPC + lane];
            atomicAdd(&cntN[val >> 17], 1);
        }
    }
    __syncthreads();

    int vc = 0;
    if (t < 256) { vc = cntN[t]; sscan[t] = vc; }
    __syncthreads();
    #pragma unroll
    for (int off = 1; off < 256; off <<= 1) {
        int u = 0;
        if (t < 256 && t >= off) u = sscan[t - off];
        __syncthreads();
        if (t < 256) sscan[t] += u;
        __syncthreads();
    }
    if (t < 256) { rsN[t] = sscan[t] - vc; curN[t] = sscan[t] - vc; }
    __syncthreads();

    // walk 2: place + exp
    for (int c = wid; c < nblkP; c += 16) {
        int cc = bhist[b * nblkP + c];
        if (lane < cc) {
            int val = chunks[((size_t)b * nblkP + c) * CAPC + lane];
            int n8 = val >> 17;
            int sidx = val & 0x1FFFF;
            int pos = atomicAdd(&curN[n8], 1);
            sSrc[pos] = sidx;
            float e = s_src[sidx] + s_dst[nodeBase + n8];
            e = (e > 0.f) ? e : e * NEG_SLOPE;
            xs[pos] = __expf(e);
        }
    }
    __syncthreads();

    // phase C: quad-per-node, 4 passes x (16 waves x 4 quads) = 256 nodes
    const short* zb = (const short*)zbf;
    const int cl8 = (lane & 15) * 4;
    #pragma unroll
    for (int pass = 0; pass < 4; ++pass) {
        int n8 = pass * 64 + wid * 4 + (lane >> 4);
        int node = nodeBase + n8;
        int rs = rsN[n8], dg = cntN[n8];
        float a0 = 0.f, a1 = 0.f, a2 = 0.f, a3 = 0.f, den = 0.f;
        int e = 0;
        for (; e + 4 <= dg; e += 4) {
            int i0 = rs + e;
            int ss0 = sSrc[i0], ss1 = sSrc[i0+1], ss2 = sSrc[i0+2], ss3 = sSrc[i0+3];
            float x0 = xs[i0], x1 = xs[i0+1], x2 = xs[i0+2], x3 = xs[i0+3];
            short4v z0 = *(const short4v*)(zb + ((size_t)(unsigned)ss0 << 6) + cl8);
            short4v z1 = *(const short4v*)(zb + ((size_t)(unsigned)ss1 << 6) + cl8);
            short4v z2 = *(const short4v*)(zb + ((size_t)(unsigned)ss2 << 6) + cl8);
            short4v z3 = *(const short4v*)(zb + ((size_t)(unsigned)ss3 << 6) + cl8);
            den += (x0 + x1) + (x2 + x3);
            a0 = fmaf(x0, bf2f((unsigned short)z0[0]), a0);
            a1 = fmaf(x0, bf2f((unsigned short)z0[1]), a1);
            a2 = fmaf(x0, bf2f((unsigned short)z0[2]), a2);
            a3 = fmaf(x0, bf2f((unsigned short)z0[3]), a3);
            a0 = fmaf(x1, bf2f((unsigned short)z1[0]), a0);
            a1 = fmaf(x1, bf2f((unsigned short)z1[1]), a1);
            a2 = fmaf(x1, bf2f((unsigned short)z1[2]), a2);
            a3 = fmaf(x1, bf2f((unsigned short)z1[3]), a3);
            a0 = fmaf(x2, bf2f((unsigned short)z2[0]), a0);
            a1 = fmaf(x2, bf2f((unsigned short)z2[1]), a1);
            a2 = fmaf(x2, bf2f((unsigned short)z2[2]), a2);
            a3 = fmaf(x2, bf2f((unsigned short)z2[3]), a3);
            a0 = fmaf(x3, bf2f((unsigned short)z3[0]), a0);
            a1 = fmaf(x3, bf2f((unsigned short)z3[1]), a1);
            a2 = fmaf(x3, bf2f((unsigned short)z3[2]), a2);
            a3 = fmaf(x3, bf2f((unsigned short)z3[3]), a3);
        }
        for (; e < dg; ++e) {
            int i0 = rs + e;
            int ss0 = sSrc[i0];
            float x0 = xs[i0];
            short4v z0 = *(const short4v*)(zb + ((size_t)(unsigned)ss0 << 6) + cl8);
            den += x0;
            a0 = fmaf(x0, bf2f((unsigned short)z0[0]), a0);
            a1 = fmaf(x0, bf2f((unsigned short)z0[1]), a1);
            a2 = fmaf(x0, bf2f((unsigned short)z0[2]), a2);
            a3 = fmaf(x0, bf2f((unsigned short)z0[3]), a3);
        }
        if (node < N) {
            float4e o;
            if (dg > 0) {
                float inv = 1.f / den;
                o[0] = a0 * inv; o[1] = a1 * inv; o[2] = a2 * inv; o[3] = a3 * inv;
            } else {
                o[0] = 0.f; o[1] = 0.f; o[2] = 0.f; o[3] = 0.f;
            }
            *(float4e*)(out + (size_t)node * OUT_DIM + cl8) = o;
        }
    }
}

extern "C" void kernel_launch(void* const* d_in, const int* in_sizes, int n_in,
                              void* d_out, int out_size, void* d_ws, size_t ws_size,
                              hipStream_t stream) {
    const float* h   = (const float*)d_in[0];
    const int*   src = (const int*)d_in[1];
    const int*   dst = (const int*)d_in[2];
    const float* Wf  = (const float*)d_in[3];
    const float* Wa  = (const float*)d_in[4];
    const int N = in_sizes[0] / NODE_DIM;
    const int E = in_sizes[1];
    float* out = (float*)d_out;

    const int PB    = (N + 63) / 64;            // proj blocks (782)
    const int nblkP = (E + EPB - 1) / EPB;      // partition blocks (196)
    const int nbB   = (N + 255) / 256;          // buckets (196)

    char* ws = (char*)d_ws;
    size_t off = 0;
    int* chunks = (int*)(ws + off);             off += (size_t)256 * nblkP * CAPC * sizeof(int);
    int* bhist  = (int*)(ws + off);             off += (size_t)256 * nblkP * sizeof(int);
    unsigned short* zbf = (unsigned short*)(ws + off); off += (size_t)N * OUT_DIM * sizeof(unsigned short);
    float* s_src = (float*)(ws + off);          off += (size_t)N * sizeof(float);
    float* s_dst = (float*)(ws + off);          off += (size_t)N * sizeof(float);

    k_proj_part<<<PB + nblkP, 256, 0, stream>>>(h, Wf, Wa, zbf, s_src, s_dst,
                                                src, dst, chunks, bhist, N, E, PB, nblkP);
    // ATTRIBUTION: 3x identical idempotent launches; dur - 119.8 = 2*t(k2)
    k_bucket_agg<<<nbB, 1024, 0, stream>>>(chunks, bhist, s_src, s_dst, zbf, out, N, nblkP);
    k_bucket_agg<<<nbB, 1024, 0, stream>>>(chunks, bhist, s_src, s_dst, zbf, out, N, nblkP);
    k_bucket_agg<<<nbB, 1024, 0, stream>>>(chunks, bhist, s_src, s_dst, zbf, out, N, nblkP);
}

// Round 15
// 119.434 us; speedup vs baseline: 1.5230x; 1.5230x over previous
//
#include <hip/hip_runtime.h>

// ============================================================================
// r15 = r8/r14-verbatim pipeline with ONE change: in the proj path, h-row
// loads are issued BEFORE the W LDS-stage (r9's k1 structure), so their HBM
// latency hides under the W-stage + barrier. r14's attribution: t(k2)=31.1us,
// C+t(k1)=88.8 -> t(k1_r8)~37; r9 cross-check: t(k1_r9) ~12.5us faster, and
// h-prefetch is the portable half of that delta.
// ============================================================================

#define NODE_DIM 128
#define OUT_DIM  64
#define NEG_SLOPE 0.01f
#define EPB   4096     // edges per partition block (256 thr x 16)
#define CAPC  64       // capacity per (bucket, partition-block) chunk (mean ~21, 9.4-sigma)
#define MAXB  4800     // max edges per bucket staged in LDS (mean 4096, +11 sigma)

typedef __attribute__((ext_vector_type(8))) short short8;
typedef __attribute__((ext_vector_type(4))) short short4v;
typedef __attribute__((ext_vector_type(4))) float float4e;

__device__ __forceinline__ unsigned short f2bf(float f) {
    unsigned u = __float_as_uint(f);
    unsigned r = (u + 0x7FFFu + ((u >> 16) & 1u)) >> 16;
    return (unsigned short)r;
}
__device__ __forceinline__ float bf2f(unsigned short v) {
    return __uint_as_float((unsigned)v << 16);
}
__device__ __forceinline__ void split_bf(float v, short& hi, short& lo) {
    unsigned short h = f2bf(v);
    float r = v - bf2f(h);
    hi = (short)h;
    lo = (short)f2bf(r);
}

// ---- K1: blocks [0,PB): MFMA projection; blocks [PB,PB+nblkP): partition ---
__global__ __launch_bounds__(256) void k_proj_part(
    const float* __restrict__ h, const float* __restrict__ Wf,
    const float* __restrict__ Wa,
    unsigned short* __restrict__ zbf,
    float* __restrict__ s_src, float* __restrict__ s_dst,
    const int* __restrict__ src, const int* __restrict__ dst,
    int* __restrict__ chunks, int* __restrict__ bhist,
    int N, int E, int PB, int nblkP)
{
    __shared__ union {
        short w[16384];                 // [0..8191]=hi, [8192..16383]=lo (frag order)
        unsigned short zt[4][16][68];   // per-wave transpose tile (aliased AFTER barrier)
    } uni;
    __shared__ int cnt[256];

    if (blockIdx.x >= (unsigned)PB) {
        const int blk = blockIdx.x - PB;
        const int t = threadIdx.x;
        cnt[t] = 0;
        __syncthreads();
        const int e0 = blk * EPB + t * 16;
        if (e0 < E) {
            int ne = E - e0; if (ne > 16) ne = 16;
            if (ne == 16) {
                int db[16], sb[16];
                const int4* dp = (const int4*)(dst + e0);
                const int4* sp = (const int4*)(src + e0);
                #pragma unroll
                for (int q = 0; q < 4; ++q) {
                    int4 dv = dp[q], svv = sp[q];
                    db[q*4+0]=dv.x; db[q*4+1]=dv.y; db[q*4+2]=dv.z; db[q*4+3]=dv.w;
                    sb[q*4+0]=svv.x; sb[q*4+1]=svv.y; sb[q*4+2]=svv.z; sb[q*4+3]=svv.w;
                }
                #pragma unroll
                for (int k = 0; k < 16; ++k) {
                    int d = db[k];
                    int bk = d >> 8;
                    int r = atomicAdd(&cnt[bk], 1);
                    if (r < CAPC)
                        chunks[((size_t)bk * nblkP + blk) * CAPC + r] = ((d & 255) << 17) | sb[k];
                }
            } else {
                for (int k = 0; k < ne; ++k) {
                    int d = dst[e0 + k];
                    int bk = d >> 8;
                    int r = atomicAdd(&cnt[bk], 1);
                    if (r < CAPC)
                        chunks[((size_t)bk * nblkP + blk) * CAPC + r] = ((d & 255) << 17) | src[e0 + k];
                }
            }
        }
        __syncthreads();
        bhist[t * nblkP + blk] = (cnt[t] < CAPC) ? cnt[t] : CAPC;
        return;
    }

    const int t    = threadIdx.x;
    const int wv   = t >> 6;
    const int lane = t & 63;
    const int m    = lane & 15;
    const int quad = lane >> 4;
    const int row0 = blockIdx.x * 64 + wv * 16;

    // --- h loads FIRST: HBM latency hides under the W stage below (r9) -----
    int rowc = row0 + m; if (rowc > N - 1) rowc = N - 1;
    const float* hrow = h + (size_t)rowc * NODE_DIM;
    float4e hreg[8];
    #pragma unroll
    for (int t4 = 0; t4 < 4; ++t4) {
        hreg[t4 * 2]     = *(const float4e*)(hrow + t4 * 32 + quad * 8);
        hreg[t4 * 2 + 1] = *(const float4e*)(hrow + t4 * 32 + quad * 8 + 4);
    }

    // --- cooperative W stage -> LDS (frag order) ----------------------------
    {
        short* wh = uni.w;
        short* wl = uni.w + 8192;
        for (int s = t; s < 1024; s += 256) {
            int combo = s >> 6;
            int ln    = s & 63;
            int c = combo >> 2, t4 = combo & 3;
            int col = c * 16 + (ln & 15);
            int kq  = t4 * 32 + (ln >> 4) * 8;
            #pragma unroll
            for (int j = 0; j < 8; ++j) {
                short hi, lo;
                split_bf(Wf[(kq + j) * OUT_DIM + col], hi, lo);
                wh[s * 8 + j] = hi;
                wl[s * 8 + j] = lo;
            }
        }
    }
    __syncthreads();

    short8 Ahi[4], Alo[4];
    #pragma unroll
    for (int t4 = 0; t4 < 4; ++t4) {
        #pragma unroll
        for (int j = 0; j < 4; ++j) {
            short hi, lo;
            split_bf(hreg[t4 * 2][j], hi, lo);
            Ahi[t4][j] = hi; Alo[t4][j] = lo;
            split_bf(hreg[t4 * 2 + 1][j], hi, lo);
            Ahi[t4][4 + j] = hi; Alo[t4][4 + j] = lo;
        }
    }

    float ps[4] = {0.f, 0.f, 0.f, 0.f};
    float pd[4] = {0.f, 0.f, 0.f, 0.f};
    unsigned short z16[16];

    const short* wh = uni.w;
    const short* wl = uni.w + 8192;
    #pragma unroll
    for (int c = 0; c < 4; ++c) {
        float4e acc = {0.f, 0.f, 0.f, 0.f};
        #pragma unroll
        for (int t4 = 0; t4 < 4; ++t4) {
            int slot = (c * 4 + t4) * 64 + lane;
            short8 bh = *(const short8*)(wh + slot * 8);   // ds_read_b128, conflict-free
            short8 bl = *(const short8*)(wl + slot * 8);
            acc = __builtin_amdgcn_mfma_f32_16x16x32_bf16(Alo[t4], bh, acc, 0, 0, 0);
            acc = __builtin_amdgcn_mfma_f32_16x16x32_bf16(Ahi[t4], bl, acc, 0, 0, 0);
            acc = __builtin_amdgcn_mfma_f32_16x16x32_bf16(Ahi[t4], bh, acc, 0, 0, 0);
        }
        int col = c * 16 + m;
        float was = Wa[col];
        float wad = Wa[OUT_DIM + col];
        #pragma unroll
        for (int r = 0; r < 4; ++r) {
            z16[c * 4 + r] = f2bf(acc[r]);
            ps[r] = fmaf(acc[r], was, ps[r]);
            pd[r] = fmaf(acc[r], wad, pd[r]);
        }
    }

    #pragma unroll
    for (int r = 0; r < 4; ++r) {
        #pragma unroll
        for (int off = 1; off < 16; off <<= 1) {
            ps[r] += __shfl_xor(ps[r], off, 64);
            pd[r] += __shfl_xor(pd[r], off, 64);
        }
    }
    if (m == 0) {
        #pragma unroll
        for (int r = 0; r < 4; ++r) {
            int nrow = row0 + quad * 4 + r;
            if (nrow < N) { s_src[nrow] = ps[r]; s_dst[nrow] = pd[r]; }
        }
    }

    // --- zbf epilogue: transpose via LDS, 2 coalesced short8 stores/wave ----
    __syncthreads();     // all waves done reading W before aliasing uni
    {
        unsigned short (*zt)[68] = uni.zt[wv];
        #pragma unroll
        for (int c = 0; c < 4; ++c)
            #pragma unroll
            for (int r = 0; r < 4; ++r)
                zt[quad * 4 + r][c * 16 + m] = z16[c * 4 + r];
        short* zb = (short*)zbf;
        #pragma unroll
        for (int i = 0; i < 2; ++i) {
            int r    = i * 8 + (lane >> 3);
            int colb = (lane & 7) * 8;
            short8 zz = *(const short8*)&zt[r][colb];
            int grow = row0 + r;
            if (grow < N)
                *(short8*)(zb + (size_t)grow * OUT_DIM + colb) = zz;
        }
    }
}

// ---- K2: one block per 256-node bucket, 1024 threads (r8 verbatim) ---------
// Phase C: quad-per-node -- EACH LANE of a quad privately accumulates its 4
// output cols AND a complete private den. NO cross-lane reduction.
__global__ __launch_bounds__(1024) void k_bucket_agg(
    const int* __restrict__ chunks, const int* __restrict__ bhist,
    const float* __restrict__ s_src, const float* __restrict__ s_dst,
    const unsigned short* __restrict__ zbf,
    float* __restrict__ out, int N, int nblkP)
{
    __shared__ int   sSrc[MAXB];
    __shared__ float xs[MAXB];
    __shared__ int cntN[256], rsN[256], curN[256], sscan[256];
    const int b = blockIdx.x;
    const int t = threadIdx.x;
    const int wid = t >> 6, lane = t & 63;
    const int nodeBase = b * 256;

    if (t < 256) cntN[t] = 0;
    __syncthreads();

    // walk 1: count per node
    for (int c = wid; c < nblkP; c += 16) {
        int cc = bhist[b * nblkP + c];
        if (lane < cc) {
            int val = chunks[((size_t)b * nblkP + c) * CAPC + lane];
            atomicAdd(&cntN[val >> 17], 1);
        }
    }
    __syncthreads();

    int vc = 0;
    if (t < 256) { vc = cntN[t]; sscan[t] = vc; }
    __syncthreads();
    #pragma unroll
    for (int off = 1; off < 256; off <<= 1) {
        int u = 0;
        if (t < 256 && t >= off) u = sscan[t - off];
        __syncthreads();
        if (t < 256) sscan[t] += u;
        __syncthreads();
    }
    if (t < 256) { rsN[t] = sscan[t] - vc; curN[t] = sscan[t] - vc; }
    __syncthreads();

    // walk 2: place + exp
    for (int c = wid; c < nblkP; c += 16) {
        int cc = bhist[b * nblkP + c];
        if (lane < cc) {
            int val = chunks[((size_t)b * nblkP + c) * CAPC + lane];
            int n8 = val >> 17;
            int sidx = val & 0x1FFFF;
            int pos = atomicAdd(&curN[n8], 1);
            sSrc[pos] = sidx;
            float e = s_src[sidx] + s_dst[nodeBase + n8];
            e = (e > 0.f) ? e : e * NEG_SLOPE;
            xs[pos] = __expf(e);
        }
    }
    __syncthreads();

    // phase C: quad-per-node, 4 passes x (16 waves x 4 quads) = 256 nodes
    const short* zb = (const short*)zbf;
    const int cl8 = (lane & 15) * 4;
    #pragma unroll
    for (int pass = 0; pass < 4; ++pass) {
        int n8 = pass * 64 + wid * 4 + (lane >> 4);
        int node = nodeBase + n8;
        int rs = rsN[n8], dg = cntN[n8];
        float a0 = 0.f, a1 = 0.f, a2 = 0.f, a3 = 0.f, den = 0.f;
        int e = 0;
        for (; e + 4 <= dg; e += 4) {
            int i0 = rs + e;
            int ss0 = sSrc[i0], ss1 = sSrc[i0+1], ss2 = sSrc[i0+2], ss3 = sSrc[i0+3];
            float x0 = xs[i0], x1 = xs[i0+1], x2 = xs[i0+2], x3 = xs[i0+3];
            short4v z0 = *(const short4v*)(zb + ((size_t)(unsigned)ss0 << 6) + cl8);
            short4v z1 = *(const short4v*)(zb + ((size_t)(unsigned)ss1 << 6) + cl8);
            short4v z2 = *(const short4v*)(zb + ((size_t)(unsigned)ss2 << 6) + cl8);
            short4v z3 = *(const short4v*)(zb + ((size_t)(unsigned)ss3 << 6) + cl8);
            den += (x0 + x1) + (x2 + x3);
            a0 = fmaf(x0, bf2f((unsigned short)z0[0]), a0);
            a1 = fmaf(x0, bf2f((unsigned short)z0[1]), a1);
            a2 = fmaf(x0, bf2f((unsigned short)z0[2]), a2);
            a3 = fmaf(x0, bf2f((unsigned short)z0[3]), a3);
            a0 = fmaf(x1, bf2f((unsigned short)z1[0]), a0);
            a1 = fmaf(x1, bf2f((unsigned short)z1[1]), a1);
            a2 = fmaf(x1, bf2f((unsigned short)z1[2]), a2);
            a3 = fmaf(x1, bf2f((unsigned short)z1[3]), a3);
            a0 = fmaf(x2, bf2f((unsigned short)z2[0]), a0);
            a1 = fmaf(x2, bf2f((unsigned short)z2[1]), a1);
            a2 = fmaf(x2, bf2f((unsigned short)z2[2]), a2);
            a3 = fmaf(x2, bf2f((unsigned short)z2[3]), a3);
            a0 = fmaf(x3, bf2f((unsigned short)z3[0]), a0);
            a1 = fmaf(x3, bf2f((unsigned short)z3[1]), a1);
            a2 = fmaf(x3, bf2f((unsigned short)z3[2]), a2);
            a3 = fmaf(x3, bf2f((unsigned short)z3[3]), a3);
        }
        for (; e < dg; ++e) {
            int i0 = rs + e;
            int ss0 = sSrc[i0];
            float x0 = xs[i0];
            short4v z0 = *(const short4v*)(zb + ((size_t)(unsigned)ss0 << 6) + cl8);
            den += x0;
            a0 = fmaf(x0, bf2f((unsigned short)z0[0]), a0);
            a1 = fmaf(x0, bf2f((unsigned short)z0[1]), a1);
            a2 = fmaf(x0, bf2f((unsigned short)z0[2]), a2);
            a3 = fmaf(x0, bf2f((unsigned short)z0[3]), a3);
        }
        if (node < N) {
            float4e o;
            if (dg > 0) {
                float inv = 1.f / den;
                o[0] = a0 * inv; o[1] = a1 * inv; o[2] = a2 * inv; o[3] = a3 * inv;
            } else {
                o[0] = 0.f; o[1] = 0.f; o[2] = 0.f; o[3] = 0.f;
            }
            *(float4e*)(out + (size_t)node * OUT_DIM + cl8) = o;
        }
    }
}

extern "C" void kernel_launch(void* const* d_in, const int* in_sizes, int n_in,
                              void* d_out, int out_size, void* d_ws, size_t ws_size,
                              hipStream_t stream) {
    const float* h   = (const float*)d_in[0];
    const int*   src = (const int*)d_in[1];
    const int*   dst = (const int*)d_in[2];
    const float* Wf  = (const float*)d_in[3];
    const float* Wa  = (const float*)d_in[4];
    const int N = in_sizes[0] / NODE_DIM;
    const int E = in_sizes[1];
    float* out = (float*)d_out;

    const int PB    = (N + 63) / 64;            // proj blocks (782)
    const int nblkP = (E + EPB - 1) / EPB;      // partition blocks (196)
    const int nbB   = (N + 255) / 256;          // buckets (196)

    char* ws = (char*)d_ws;
    size_t off = 0;
    int* chunks = (int*)(ws + off);             off += (size_t)256 * nblkP * CAPC * sizeof(int);
    int* bhist  = (int*)(ws + off);             off += (size_t)256 * nblkP * sizeof(int);
    unsigned short* zbf = (unsigned short*)(ws + off); off += (size_t)N * OUT_DIM * sizeof(unsigned short);
    float* s_src = (float*)(ws + off);          off += (size_t)N * sizeof(float);
    float* s_dst = (float*)(ws + off);          off += (size_t)N * sizeof(float);

    k_proj_part<<<PB + nblkP, 256, 0, stream>>>(h, Wf, Wa, zbf, s_src, s_dst,
                                                src, dst, chunks, bhist, N, E, PB, nblkP);
    k_bucket_agg<<<nbB, 1024, 0, stream>>>(chunks, bhist, s_src, s_dst, zbf, out, N, nblkP);
}